// Round 15
// baseline (1411.287 us; speedup 1.0000x reference)
//
#include <hip/hip_runtime.h>

#define T_MAX 256
#define BATCH 32
#define NC 64
#define BEAM 16
#define TOPK 4
#define NEG (-1.0e9f)
#define FLTMAX 3.402823466e+38f

typedef unsigned long long u64;
typedef unsigned int u32;

// Matches jnp.logaddexp exactly: max + log1p(exp(-|a-b|))
__device__ __forceinline__ float log_add_exp(float a, float b) {
    float m = fmaxf(a, b);
    float d = fabsf(a - b);
    return m + log1pf(expf(-d));
}

// Wave-uniform lane reads: VALU->SGPR, no DS pipe.
__device__ __forceinline__ u32 rdl_u32(u32 v, int sl) {
    return (u32)__builtin_amdgcn_readlane((int)v, sl);
}
__device__ __forceinline__ float rdl_f(float v, int sl) {
    return __uint_as_float(rdl_u32(__float_as_uint(v), sl));
}
__device__ __forceinline__ int rdl_i(int v, int sl) {
    return __builtin_amdgcn_readlane(v, sl);
}

// u64 key: monotone float in [42:11], (2047-flat) in [10:0].
// Larger key == (larger value, then smaller flat) -> lax.top_k stable order.
// All real keys > 0, so 0 is a safe null (sinks in descending sort).
__device__ __forceinline__ u64 pack_key(float v, int flat) {
    u32 u = __float_as_uint(v);
    u32 k = (u & 0x80000000u) ? ~u : (u | 0x80000000u);
    return ((u64)k << 11) | (u64)(2047 - flat);
}
__device__ __forceinline__ float key_val(u64 key) {
    u32 k = (u32)(key >> 11);
    u32 u = (k & 0x80000000u) ? (k ^ 0x80000000u) : ~k;
    return __uint_as_float(u);
}
__device__ __forceinline__ int key_flat(u64 key) {
    return 2047 - (int)(key & 2047u);
}
__device__ __forceinline__ u64 max64(u64 a, u64 b) { return a > b ? a : b; }
__device__ __forceinline__ u64 min64(u64 a, u64 b) { return a < b ? a : b; }

// Bitonic sort of 16 register-resident u64 keys, descending (overflow fallback).
__device__ __forceinline__ void sort16_desc_u64(u64 (&a)[BEAM]) {
    #pragma unroll
    for (int k = 2; k <= 16; k <<= 1) {
        #pragma unroll
        for (int j = k >> 1; j > 0; j >>= 1) {
            #pragma unroll
            for (int i = 0; i < 16; ++i) {
                int l = i ^ j;
                if (l > i) {
                    const bool desc = ((i & k) == 0);
                    u64 x = a[i], y = a[l];
                    bool sw = desc ? (x < y) : (x > y);
                    a[i] = sw ? y : x;
                    a[l] = sw ? x : y;
                }
            }
        }
    }
}

// Bitonic sort of 16 register-resident f32 values, descending.
__device__ __forceinline__ void sort16_desc_f32(float (&a)[BEAM]) {
    #pragma unroll
    for (int k = 2; k <= 16; k <<= 1) {
        #pragma unroll
        for (int j = k >> 1; j > 0; j >>= 1) {
            #pragma unroll
            for (int i = 0; i < 16; ++i) {
                int l = i ^ j;
                if (l > i) {
                    const bool desc = ((i & k) == 0);
                    float x = a[i], y = a[l];
                    float mx = fmaxf(x, y), mn = fminf(x, y);
                    a[i] = desc ? mx : mn;
                    a[l] = desc ? mn : mx;
                }
            }
        }
    }
}

// One value-only butterfly merge level: 16 independent swizzles (batched),
// then register-only bitonic cleanup.
template <int M>
__device__ __forceinline__ void bf_level_f32(float (&a)[BEAM]) {
    float c[BEAM];
    #pragma unroll
    for (int i = 0; i < BEAM; ++i)
        c[i] = __shfl_xor(a[BEAM - 1 - i], M, 64);
    #pragma unroll
    for (int i = 0; i < BEAM; ++i)
        c[i] = fmaxf(a[i], c[i]);
    #pragma unroll
    for (int j = 8; j > 0; j >>= 1) {
        #pragma unroll
        for (int i = 0; i < BEAM; ++i)
            if ((i & j) == 0) {
                float x = c[i], y = c[i | j];
                c[i]     = fmaxf(x, y);
                c[i | j] = fminf(x, y);
            }
    }
    #pragma unroll
    for (int i = 0; i < BEAM; ++i) a[i] = c[i];
}

// Wave-wide count of candidates >= th (17 per lane: 16 ext + 1 stay).
__device__ __forceinline__ int count_ge(const float (&ev)[BEAM], float st_tot,
                                        int lane, float th) {
    int cf = (lane < BEAM && st_tot >= th) ? 1 : 0;
    #pragma unroll
    for (int s = 0; s < BEAM; ++s) cf += (ev[s] >= th) ? 1 : 0;
    #pragma unroll
    for (int m = 1; m < 64; m <<= 1) cf += __shfl_xor(cf, m, 64);
    return cf;
}

// Fully parallel log-softmax precompute: one 64-lane block per (t,b) row.
__global__ __launch_bounds__(64) void softmax_kernel(const float* __restrict__ data,
                                                     float* __restrict__ lp_out) {
    const int row = blockIdx.x;
    const int lane = threadIdx.x;
    float x = data[row * NC + lane];
    float mx = x;
    #pragma unroll
    for (int m = 1; m < 64; m <<= 1) mx = fmaxf(mx, __shfl_xor(mx, m, 64));
    float sum = expf(x - mx);
    #pragma unroll
    for (int m = 1; m < 64; m <<= 1) sum += __shfl_xor(sum, m, 64);
    lp_out[row * NC + lane] = (x - mx) - logf(sum);
}

template <bool PRE>
__global__ __launch_bounds__(64, 1) void ctc_beam_kernel(
        const float* __restrict__ data,      // [T, B, C] logits
        const float* __restrict__ lp_pre,    // [T, B, C] log-probs (if PRE)
        const int*   __restrict__ data_len,  // [B]
        float*       __restrict__ out)       // [B*4 probs][B*4 lens][B*4*256 labels]
{
    const int b    = blockIdx.x;
    const int lane = threadIdx.x;

    __shared__ u32 mmask[BEAM * 2];               // per-i 64-bit (i,c) match mask
    __shared__ u64 slotsL[64];                    // selected-candidate keys
    __shared__ u32 cntL;                          // selected-candidate count
    __shared__ unsigned short hist[T_MAX * BEAM]; // [11:8]=parent, bit7=stay, [6:0]=char
    __shared__ int ord4[TOPK];
    __shared__ float val4[TOPK];

    int len = data_len[b];
    if (len < 0) len = 0;
    if (len > T_MAX) len = T_MAX;

    // ---- beam state in registers (meaningful in lanes < 16) ----
    float pb  = (lane == 0) ? 0.0f : NEG;
    float pnb = NEG;
    u32 h1 = 0u, h2 = 0u;
    int lenb = 0, lastb = -1, actb = (lane == 0) ? 1 : 0;
    float spread = 1.0e30f;   // speculative-threshold width; forces exact path at t=0

    const float* src = PRE ? lp_pre : data;
    float xpref = (len > 0) ? src[b * NC + lane] : 0.f;   // prefetch row 0

    #pragma unroll 1
    for (int t = 0; t < len; ++t) {
        float x = xpref;
        int tn = (t + 1 < len) ? (t + 1) : t;
        xpref = src[(tn * BATCH + b) * NC + lane];   // prefetch next row early

        float lp;
        if (PRE) {
            lp = x;
        } else {
            float mx = x;
            #pragma unroll
            for (int m = 1; m < 64; m <<= 1) mx = fmaxf(mx, __shfl_xor(mx, m, 64));
            float sum = expf(x - mx);
            #pragma unroll
            for (int m = 1; m < 64; m <<= 1) sum += __shfl_xor(sum, m, 64);
            lp = (x - mx) - logf(sum);
        }
        float lp0 = rdl_f(lp, 0);

        // ---- stay candidates (lanes < 16 meaningful) ----
        float tot = log_add_exp(pb, pnb);
        int lastc = (lastb < 0) ? 0 : (lastb & 63);
        float lplast = __shfl(lp, lastc, 64);        // variable lane: bpermute (1 DS)
        float st_pb   = tot + lp0;
        float st_pnb0 = (lenb > 0) ? (pnb + lplast) : NEG;

        // ---- hash matches via readlane (closed form: <=1 c per (i,j)), no DS ----
        int cm[BEAM];
        bool anym_l = false;
        #pragma unroll
        for (int i = 0; i < BEAM; ++i) {
            u32 h1i = rdl_u32(h1, i);
            u32 h2i = rdl_u32(h2, i);
            u32 c1 = h1 - h1i * 1000003u;
            u32 c2 = h2 - h2i * 69069u;
            int cmv = -1;
            if (lane < BEAM && actb && c1 == c2 && c1 >= 1u && c1 <= 64u)
                cmv = (int)c1 - 1;
            cm[i] = cmv;
            anym_l = anym_l || (cmv >= 0);
        }
        u64 anym = __ballot(anym_l);                 // wave-uniform

        // ---- extend candidates via readlane (lane = class c), no DS ----
        float e0s[BEAM];
        int la = (lastb & 0xFF) | ((actb & 1) << 8);
        #pragma unroll
        for (int i = 0; i < BEAM; ++i) {
            float tot_i = rdl_f(tot, i);
            float pb_i  = rdl_f(pb, i);
            int   la_i  = rdl_i(la, i);
            int last_i = (int)((signed char)(la_i & 0xFF));
            int act_i  = (la_i >> 8) & 1;
            float e0 = ((lane == last_i) ? pb_i : tot_i) + lp;
            if (lane == 0 || !act_i) e0 = NEG;
            e0s[i] = e0;
        }

        // ---- exclusion + duplicate-prefix fold (wave-uniform gated) ----
        float ev[BEAM];
        float merged = NEG;
        if (anym) {
            if (lane < BEAM * 2) mmask[lane] = 0u;
            __syncthreads();
            #pragma unroll
            for (int i = 0; i < BEAM; ++i)
                if (cm[i] >= 0)
                    atomicOr(&mmask[i * 2 + (cm[i] >> 5)], 1u << (cm[i] & 31));
            __syncthreads();
            const int half = lane >> 5, bit = lane & 31;
            u32 mybits = 0;
            #pragma unroll
            for (int i = 0; i < BEAM; ++i)
                mybits |= ((mmask[i * 2 + half] >> bit) & 1u) << i;
            #pragma unroll
            for (int s = 0; s < BEAM; ++s)
                ev[s] = ((mybits >> s) & 1u) ? NEG : e0s[s];
            float amax = NEG;
            float vm[BEAM];
            #pragma unroll
            for (int i = 0; i < BEAM; ++i) {
                int gsrc = (cm[i] >= 0) ? cm[i] : 0;
                vm[i] = __shfl(e0s[i], gsrc, 64);    // bpermute gather
                if (cm[i] >= 0) amax = fmaxf(amax, vm[i]);
            }
            if (amax > NEG) {
                float sm = 0.f;
                #pragma unroll
                for (int i = 0; i < BEAM; ++i)   // ascending i == flat order
                    if (cm[i] >= 0) sm += expf(vm[i] - amax);
                merged = amax + logf(sm);
            }
        } else {
            #pragma unroll
            for (int s = 0; s < BEAM; ++s) ev[s] = e0s[s];
        }

        float st_pnb = log_add_exp(st_pnb0, merged);
        float st_tot = log_add_exp(st_pb, st_pnb);

        // ---- speculative threshold ladder (exact-checked, correct at any
        //      hit rate): count(>=theta) >= 16 ==> theta <= v16 ==> superset
        //      of the true top-16; count <= 64 fits the exact sorters below. ----
        float mxl = (lane < BEAM) ? st_tot : NEG;
        #pragma unroll
        for (int s = 0; s < BEAM; ++s) mxl = fmaxf(mxl, ev[s]);
        float vmax = mxl;
        #pragma unroll
        for (int m = 1; m < 64; m <<= 1) vmax = fmaxf(vmax, __shfl_xor(vmax, m, 64));

        float thr;
        bool have_thr = false;
        {
            float theta = vmax - spread;
            int cf = count_ge(ev, st_tot, lane, theta);
            if (cf >= BEAM && cf <= 64) { thr = theta; have_thr = true; }
            else if (cf < BEAM) {        // too tight: one wider retry
                float theta2 = vmax - (2.5f * spread + 1.0f);
                int cf2 = count_ge(ev, st_tot, lane, theta2);
                if (cf2 >= BEAM && cf2 <= 64) { thr = theta2; have_thr = true; }
            }
        }
        if (!have_thr) {
            // ---- exact phase-1: v16 = 16th-largest of the true multiset ----
            float a[BEAM];
            #pragma unroll
            for (int s = 0; s < BEAM; ++s) a[s] = ev[s];
            sort16_desc_f32(a);
            {   // fold stay value into local sorted list
                float sv = (lane < BEAM) ? st_tot : NEG;
                #pragma unroll
                for (int i = BEAM - 1; i >= 1; --i)
                    a[i] = fmaxf(a[i], fminf(a[i - 1], sv));
                a[0] = fmaxf(a[0], sv);
            }
            bf_level_f32<1>(a);  bf_level_f32<2>(a);  bf_level_f32<4>(a);
            bf_level_f32<8>(a);  bf_level_f32<16>(a); bf_level_f32<32>(a);
            thr = a[15];
        }

        // ---- phase 2: scatter all candidates >= thr, exact stable sort ----
        u32 bits = 0;
        #pragma unroll
        for (int s = 0; s < BEAM; ++s)
            if (ev[s] >= thr) bits |= (1u << s);
        if (lane < BEAM && st_tot >= thr) bits |= (1u << 16);
        int mycnt = __popc(bits);
        if (lane == 0) cntL = 0u;        // same-wave DS ordering precedes atomics
        u32 base = 0;
        if (mycnt) base = atomicAdd(&cntL, (u32)mycnt);
        #pragma unroll
        for (int s = 0; s < BEAM; ++s)
            if (bits & (1u << s)) {
                if (base < 64u) slotsL[base] = pack_key(ev[s], BEAM + s * NC + lane);
                ++base;
            }
        if (bits & (1u << 16)) {
            if (base < 64u) slotsL[base] = pack_key(st_tot, lane);
            ++base;
        }
        __syncthreads();
        u32 totc = cntL;                 // broadcast read, wave-uniform

        int flat; float val;
        if (totc <= 32u) {
            u64 kk = (lane < 32 && (u32)lane < totc) ? slotsL[lane] : 0ull;
            // bitonic sort-32 descending in lanes 0-31 (R4-proven CE pattern);
            // lanes 32-63 mirror harmlessly (xor masks < 32 keep halves apart).
            #pragma unroll
            for (int k = 2; k <= 32; k <<= 1) {
                #pragma unroll
                for (int j = k >> 1; j >= 1; j >>= 1) {
                    bool up = ((lane & k) == 0);
                    bool km = (((lane & j) == 0) == up);
                    u64 o = (u64)__shfl_xor((long long)kk, j, 64);
                    bool take = km ? (o > kk) : (o < kk);
                    kk = take ? o : kk;
                }
            }
            flat = key_flat(kk);         // lane r (0-15) holds rank r
            val  = key_val(kk);
        } else if (totc <= 64u) {
            // ---- mid-tier: full cross-lane u64 sort-64 (exact, stable) ----
            u64 kk = ((u32)lane < totc) ? slotsL[lane] : 0ull;
            #pragma unroll
            for (int k = 2; k <= 64; k <<= 1) {
                #pragma unroll
                for (int j = k >> 1; j >= 1; j >>= 1) {
                    bool up = ((lane & k) == 0);
                    bool km = (((lane & j) == 0) == up);
                    u64 o = (u64)__shfl_xor((long long)kk, j, 64);
                    bool take = km ? (o > kk) : (o < kk);
                    kk = take ? o : kk;
                }
            }
            flat = key_flat(kk);         // lane r (0-15) holds rank r
            val  = key_val(kk);
        } else {
            // ---- exact u64 fallback (R3-proven), ~never ----
            u64 ku[BEAM];
            #pragma unroll
            for (int s = 0; s < BEAM; ++s)
                ku[s] = pack_key(ev[s], BEAM + s * NC + lane);
            sort16_desc_u64(ku);
            u64 sk = (lane < BEAM) ? pack_key(st_tot, lane) : 0ull;
            #pragma unroll
            for (int i = BEAM - 1; i >= 1; --i)
                ku[i] = max64(ku[i], min64(ku[i - 1], sk));
            ku[0] = max64(ku[0], sk);
            #pragma unroll 1
            for (int m = 1; m < 64; m <<= 1) {
                u64 c_[BEAM];
                #pragma unroll
                for (int i = 0; i < BEAM; ++i) {
                    u64 o = (u64)__shfl_xor((long long)ku[BEAM - 1 - i], m, 64);
                    c_[i] = max64(ku[i], o);
                }
                #pragma unroll
                for (int j = 8; j > 0; j >>= 1) {
                    #pragma unroll
                    for (int i = 0; i < BEAM; ++i)
                        if ((i & j) == 0) {
                            u64 xk = c_[i], yk = c_[i | j];
                            bool sw = xk < yk;
                            c_[i]     = sw ? yk : xk;
                            c_[i | j] = sw ? xk : yk;
                        }
                }
                #pragma unroll
                for (int i = 0; i < BEAM; ++i) ku[i] = c_[i];
            }
            u64 selkey = ku[0];
            #pragma unroll
            for (int i = 1; i < BEAM; ++i)
                if (lane == i) selkey = ku[i];
            flat = key_flat(selkey);
            val  = key_val(selkey);
        }

        // ---- predictor update from the EXACT selection (any path) ----
        {
            float v1n  = rdl_f(val, 0);
            float v16n = rdl_f(val, 15);
            spread = (v1n - v16n) * 1.25f + 1.0e-3f;
        }

        // ---- new state (lane k = rank-k winner) ----
        bool stay = flat < BEAM;
        int pidx = stay ? flat : ((flat - BEAM) >> 6);
        pidx &= 15;
        int cnew = stay ? 0 : ((flat - BEAM) & 63);

        // variable-index gathers (bpermute), all independent -> one wait
        float g_stpb  = __shfl(st_pb, pidx, 64);
        float g_stpnb = __shfl(st_pnb, pidx, 64);
        u32   g_h1    = (u32)__shfl((int)h1, pidx, 64);
        u32   g_h2    = (u32)__shfl((int)h2, pidx, 64);
        int   g_ll    = __shfl((lenb << 8) | (lastb & 255), pidx, 64);
        int   g_len   = g_ll >> 8;
        int   g_last  = (int)((signed char)(g_ll & 255));

        pb   = stay ? g_stpb : NEG;
        pnb  = stay ? g_stpnb : val;
        h1   = stay ? g_h1 : (g_h1 * 1000003u + (u32)(cnew + 1));
        h2   = stay ? g_h2 : (g_h2 * 69069u   + (u32)(cnew + 1));
        lenb = g_len + (stay ? 0 : 1);
        lastb = stay ? g_last : cnew;
        actb = (val > -5.0e8f) ? 1 : 0;              // vals > NEG/2
        if (lane < BEAM)
            hist[t * BEAM + lane] =
                (unsigned short)((pidx << 8) | (stay ? 0x80 : 0) | cnew);
    }
    __syncthreads();

    // ---- final stable top-4 over beam totals ----
    float ft = (lane < BEAM) ? log_add_exp(pb, pnb) : -FLTMAX;
    int fidx = (lane < BEAM) ? lane : 0x7FFFFFFF;
    for (int k = 0; k < TOPK; ++k) {
        float bv = ft; int bi = fidx;
        #pragma unroll
        for (int m = 1; m < 64; m <<= 1) {
            float ov = __shfl_xor(bv, m, 64);
            int   oi = __shfl_xor(bi, m, 64);
            if (ov > bv || (ov == bv && oi < bi)) { bv = ov; bi = oi; }
        }
        if (lane == 0) { ord4[k] = bi; val4[k] = bv; }
        if (lane == bi) ft = -FLTMAX;
    }
    __syncthreads();

    int bsel = ord4[lane & 3] & 15;
    int lensel = __shfl(lenb, bsel, 64);

    // ---- outputs: probs [B,4] | lens [B,4] | labels [B,4,256] ----
    for (int e2 = lane; e2 < TOPK * T_MAX; e2 += 64)
        out[BATCH * TOPK * 2 + b * (TOPK * T_MAX) + e2] = -1.0f;
    __syncthreads();
    if (lane < TOPK) {
        const int k = lane;
        out[b * TOPK + k] = -val4[k];
        out[BATCH * TOPK + b * TOPK + k] = (float)lensel;
        int pos = lensel - 1;
        int cur = ord4[k];
        float* lab = out + BATCH * TOPK * 2 + b * (TOPK * T_MAX) + k * T_MAX;
        for (int tt = len - 1; tt >= 0; --tt) {
            unsigned short h = hist[tt * BEAM + cur];
            if (!(h & 0x80)) { lab[pos] = (float)(h & 0x7F); --pos; }
            cur = h >> 8;
        }
    }
}

extern "C" void kernel_launch(void* const* d_in, const int* in_sizes, int n_in,
                              void* d_out, int out_size, void* d_ws, size_t ws_size,
                              hipStream_t stream) {
    const float* data = (const float*)d_in[0];
    const int* data_len = (const int*)d_in[1];
    float* out = (float*)d_out;
    const size_t lp_bytes = (size_t)T_MAX * BATCH * NC * sizeof(float);
    if (ws_size >= lp_bytes) {
        float* lp_ws = (float*)d_ws;
        softmax_kernel<<<dim3(T_MAX * BATCH), dim3(64), 0, stream>>>(data, lp_ws);
        ctc_beam_kernel<true><<<dim3(BATCH), dim3(64), 0, stream>>>(data, lp_ws, data_len, out);
    } else {
        ctc_beam_kernel<false><<<dim3(BATCH), dim3(64), 0, stream>>>(data, nullptr, data_len, out);
    }
}

// Round 16
// 1398.948 us; speedup vs baseline: 1.0088x; 1.0088x over previous
//
#include <hip/hip_runtime.h>

#define T_MAX 256
#define BATCH 32
#define NC 64
#define BEAM 16
#define TOPK 4
#define NEG (-1.0e9f)
#define FLTMAX 3.402823466e+38f

typedef unsigned long long u64;
typedef unsigned int u32;

// Matches jnp.logaddexp exactly: max + log1p(exp(-|a-b|))
__device__ __forceinline__ float log_add_exp(float a, float b) {
    float m = fmaxf(a, b);
    float d = fabsf(a - b);
    return m + log1pf(expf(-d));
}

// Wave-uniform lane reads: VALU->SGPR, no DS pipe.
__device__ __forceinline__ u32 rdl_u32(u32 v, int sl) {
    return (u32)__builtin_amdgcn_readlane((int)v, sl);
}
__device__ __forceinline__ float rdl_f(float v, int sl) {
    return __uint_as_float(rdl_u32(__float_as_uint(v), sl));
}
__device__ __forceinline__ int rdl_i(int v, int sl) {
    return __builtin_amdgcn_readlane(v, sl);
}

// u64 key: monotone float in [42:11], (2047-flat) in [10:0].
// Larger key == (larger value, then smaller flat) -> lax.top_k stable order.
// All real keys > 0, so 0 is a safe null (sinks in descending sort).
__device__ __forceinline__ u64 pack_key(float v, int flat) {
    u32 u = __float_as_uint(v);
    u32 k = (u & 0x80000000u) ? ~u : (u | 0x80000000u);
    return ((u64)k << 11) | (u64)(2047 - flat);
}
__device__ __forceinline__ float key_val(u64 key) {
    u32 k = (u32)(key >> 11);
    u32 u = (k & 0x80000000u) ? (k ^ 0x80000000u) : ~k;
    return __uint_as_float(u);
}
__device__ __forceinline__ int key_flat(u64 key) {
    return 2047 - (int)(key & 2047u);
}
__device__ __forceinline__ u64 max64(u64 a, u64 b) { return a > b ? a : b; }
__device__ __forceinline__ u64 min64(u64 a, u64 b) { return a < b ? a : b; }

// Bitonic sort of 16 register-resident u64 keys, descending (overflow fallback).
__device__ __forceinline__ void sort16_desc_u64(u64 (&a)[BEAM]) {
    #pragma unroll
    for (int k = 2; k <= 16; k <<= 1) {
        #pragma unroll
        for (int j = k >> 1; j > 0; j >>= 1) {
            #pragma unroll
            for (int i = 0; i < 16; ++i) {
                int l = i ^ j;
                if (l > i) {
                    const bool desc = ((i & k) == 0);
                    u64 x = a[i], y = a[l];
                    bool sw = desc ? (x < y) : (x > y);
                    a[i] = sw ? y : x;
                    a[l] = sw ? x : y;
                }
            }
        }
    }
}

// Bitonic sort of 16 register-resident f32 values, descending.
__device__ __forceinline__ void sort16_desc_f32(float (&a)[BEAM]) {
    #pragma unroll
    for (int k = 2; k <= 16; k <<= 1) {
        #pragma unroll
        for (int j = k >> 1; j > 0; j >>= 1) {
            #pragma unroll
            for (int i = 0; i < 16; ++i) {
                int l = i ^ j;
                if (l > i) {
                    const bool desc = ((i & k) == 0);
                    float x = a[i], y = a[l];
                    float mx = fmaxf(x, y), mn = fminf(x, y);
                    a[i] = desc ? mx : mn;
                    a[l] = desc ? mn : mx;
                }
            }
        }
    }
}

// One value-only butterfly merge level: 16 independent swizzles (batched),
// then register-only bitonic cleanup.
template <int M>
__device__ __forceinline__ void bf_level_f32(float (&a)[BEAM]) {
    float c[BEAM];
    #pragma unroll
    for (int i = 0; i < BEAM; ++i)
        c[i] = __shfl_xor(a[BEAM - 1 - i], M, 64);
    #pragma unroll
    for (int i = 0; i < BEAM; ++i)
        c[i] = fmaxf(a[i], c[i]);
    #pragma unroll
    for (int j = 8; j > 0; j >>= 1) {
        #pragma unroll
        for (int i = 0; i < BEAM; ++i)
            if ((i & j) == 0) {
                float x = c[i], y = c[i | j];
                c[i]     = fmaxf(x, y);
                c[i | j] = fminf(x, y);
            }
    }
    #pragma unroll
    for (int i = 0; i < BEAM; ++i) a[i] = c[i];
}

// Wave-wide count of candidates >= th (17 per lane: 16 ext + 1 stay).
__device__ __forceinline__ int count_ge(const float (&ev)[BEAM], float st_tot,
                                        int lane, float th) {
    int cf = (lane < BEAM && st_tot >= th) ? 1 : 0;
    #pragma unroll
    for (int s = 0; s < BEAM; ++s) cf += (ev[s] >= th) ? 1 : 0;
    #pragma unroll
    for (int m = 1; m < 64; m <<= 1) cf += __shfl_xor(cf, m, 64);
    return cf;
}

// Fully parallel log-softmax precompute: one 64-lane block per (t,b) row.
__global__ __launch_bounds__(64) void softmax_kernel(const float* __restrict__ data,
                                                     float* __restrict__ lp_out) {
    const int row = blockIdx.x;
    const int lane = threadIdx.x;
    float x = data[row * NC + lane];
    float mx = x;
    #pragma unroll
    for (int m = 1; m < 64; m <<= 1) mx = fmaxf(mx, __shfl_xor(mx, m, 64));
    float sum = expf(x - mx);
    #pragma unroll
    for (int m = 1; m < 64; m <<= 1) sum += __shfl_xor(sum, m, 64);
    lp_out[row * NC + lane] = (x - mx) - logf(sum);
}

template <bool PRE>
__global__ __launch_bounds__(64, 1) void ctc_beam_kernel(
        const float* __restrict__ data,      // [T, B, C] logits
        const float* __restrict__ lp_pre,    // [T, B, C] log-probs (if PRE)
        const int*   __restrict__ data_len,  // [B]
        float*       __restrict__ out)       // [B*4 probs][B*4 lens][B*4*256 labels]
{
    const int b    = blockIdx.x;
    const int lane = threadIdx.x;

    __shared__ u32 mmask[BEAM * 2];               // per-i 64-bit (i,c) match mask
    __shared__ u64 slotsL[64];                    // selected-candidate keys
    __shared__ u32 cntL;                          // selected-candidate count
    __shared__ unsigned short hist[T_MAX * BEAM]; // [11:8]=parent, bit7=stay, [6:0]=char
    __shared__ int ord4[TOPK];
    __shared__ float val4[TOPK];

    int len = data_len[b];
    if (len < 0) len = 0;
    if (len > T_MAX) len = T_MAX;

    // ---- beam state in registers (meaningful in lanes < 16) ----
    float pb  = (lane == 0) ? 0.0f : NEG;
    float pnb = NEG;
    u32 h1 = 0u, h2 = 0u;
    int lenb = 0, lastb = -1, actb = (lane == 0) ? 1 : 0;
    float spread = 1.0e30f;   // speculative-threshold width; forces exact path at t=0

    const float* src = PRE ? lp_pre : data;
    float xpref = (len > 0) ? src[b * NC + lane] : 0.f;   // prefetch row 0

    #pragma unroll 1
    for (int t = 0; t < len; ++t) {
        float x = xpref;
        int tn = (t + 1 < len) ? (t + 1) : t;
        xpref = src[(tn * BATCH + b) * NC + lane];   // prefetch next row early

        float lp;
        if (PRE) {
            lp = x;
        } else {
            float mx = x;
            #pragma unroll
            for (int m = 1; m < 64; m <<= 1) mx = fmaxf(mx, __shfl_xor(mx, m, 64));
            float sum = expf(x - mx);
            #pragma unroll
            for (int m = 1; m < 64; m <<= 1) sum += __shfl_xor(sum, m, 64);
            lp = (x - mx) - logf(sum);
        }
        float lp0 = rdl_f(lp, 0);

        // ---- stay candidates (lanes < 16 meaningful) ----
        float tot = log_add_exp(pb, pnb);
        int lastc = (lastb < 0) ? 0 : (lastb & 63);
        float lplast = __shfl(lp, lastc, 64);        // variable lane: bpermute (1 DS)
        float st_pb   = tot + lp0;
        float st_pnb0 = (lenb > 0) ? (pnb + lplast) : NEG;

        // ---- hash matches via readlane (closed form: <=1 c per (i,j)), no DS ----
        int cm[BEAM];
        bool anym_l = false;
        #pragma unroll
        for (int i = 0; i < BEAM; ++i) {
            u32 h1i = rdl_u32(h1, i);
            u32 h2i = rdl_u32(h2, i);
            u32 c1 = h1 - h1i * 1000003u;
            u32 c2 = h2 - h2i * 69069u;
            int cmv = -1;
            if (lane < BEAM && actb && c1 == c2 && c1 >= 1u && c1 <= 64u)
                cmv = (int)c1 - 1;
            cm[i] = cmv;
            anym_l = anym_l || (cmv >= 0);
        }
        u64 anym = __ballot(anym_l);                 // wave-uniform

        // ---- extend candidates via readlane (lane = class c), no DS ----
        float e0s[BEAM];
        int la = (lastb & 0xFF) | ((actb & 1) << 8);
        #pragma unroll
        for (int i = 0; i < BEAM; ++i) {
            float tot_i = rdl_f(tot, i);
            float pb_i  = rdl_f(pb, i);
            int   la_i  = rdl_i(la, i);
            int last_i = (int)((signed char)(la_i & 0xFF));
            int act_i  = (la_i >> 8) & 1;
            float e0 = ((lane == last_i) ? pb_i : tot_i) + lp;
            if (lane == 0 || !act_i) e0 = NEG;
            e0s[i] = e0;
        }

        // ---- exclusion + duplicate-prefix fold (wave-uniform gated) ----
        float ev[BEAM];
        float merged = NEG;
        if (anym) {
            if (lane < BEAM * 2) mmask[lane] = 0u;
            __syncthreads();
            #pragma unroll
            for (int i = 0; i < BEAM; ++i)
                if (cm[i] >= 0)
                    atomicOr(&mmask[i * 2 + (cm[i] >> 5)], 1u << (cm[i] & 31));
            __syncthreads();
            const int half = lane >> 5, bit = lane & 31;
            u32 mybits = 0;
            #pragma unroll
            for (int i = 0; i < BEAM; ++i)
                mybits |= ((mmask[i * 2 + half] >> bit) & 1u) << i;
            #pragma unroll
            for (int s = 0; s < BEAM; ++s)
                ev[s] = ((mybits >> s) & 1u) ? NEG : e0s[s];
            float amax = NEG;
            float vm[BEAM];
            #pragma unroll
            for (int i = 0; i < BEAM; ++i) {
                int gsrc = (cm[i] >= 0) ? cm[i] : 0;
                vm[i] = __shfl(e0s[i], gsrc, 64);    // bpermute gather
                if (cm[i] >= 0) amax = fmaxf(amax, vm[i]);
            }
            if (amax > NEG) {
                float sm = 0.f;
                #pragma unroll
                for (int i = 0; i < BEAM; ++i)   // ascending i == flat order
                    if (cm[i] >= 0) sm += expf(vm[i] - amax);
                merged = amax + logf(sm);
            }
        } else {
            #pragma unroll
            for (int s = 0; s < BEAM; ++s) ev[s] = e0s[s];
        }

        float st_pnb = log_add_exp(st_pnb0, merged);
        float st_tot = log_add_exp(st_pb, st_pnb);

        // ---- speculative threshold + typed retry (exact-checked; correct at
        //      any hit rate): count(>=theta) >= 16 ==> theta <= v16 ==>
        //      superset of the true top-16; count <= 32 fits exact sort-32. ----
        float mxl = (lane < BEAM) ? st_tot : NEG;
        #pragma unroll
        for (int s = 0; s < BEAM; ++s) mxl = fmaxf(mxl, ev[s]);
        float vmax = mxl;
        #pragma unroll
        for (int m = 1; m < 64; m <<= 1) vmax = fmaxf(vmax, __shfl_xor(vmax, m, 64));

        float thr;
        bool have_thr = false;
        {
            float theta = vmax - spread;
            int cf = count_ge(ev, st_tot, lane, theta);
            if (cf >= BEAM && cf <= 32) { thr = theta; have_thr = true; }
            else if (cf > 32) {          // too loose: one tighter retry
                float theta2 = vmax - 0.5f * spread;
                int cf2 = count_ge(ev, st_tot, lane, theta2);
                if (cf2 >= BEAM && cf2 <= 32) { thr = theta2; have_thr = true; }
            } else {                     // too tight: one wider retry
                float theta2 = vmax - (2.5f * spread + 1.0f);
                int cf2 = count_ge(ev, st_tot, lane, theta2);
                if (cf2 >= BEAM && cf2 <= 32) { thr = theta2; have_thr = true; }
            }
        }
        if (!have_thr) {
            // ---- exact phase-1: v16 = 16th-largest of the true multiset ----
            float a[BEAM];
            #pragma unroll
            for (int s = 0; s < BEAM; ++s) a[s] = ev[s];
            sort16_desc_f32(a);
            {   // fold stay value into local sorted list
                float sv = (lane < BEAM) ? st_tot : NEG;
                #pragma unroll
                for (int i = BEAM - 1; i >= 1; --i)
                    a[i] = fmaxf(a[i], fminf(a[i - 1], sv));
                a[0] = fmaxf(a[0], sv);
            }
            bf_level_f32<1>(a);  bf_level_f32<2>(a);  bf_level_f32<4>(a);
            bf_level_f32<8>(a);  bf_level_f32<16>(a); bf_level_f32<32>(a);
            thr = a[15];
        }

        // ---- phase 2: scatter all candidates >= thr, cross-lane sort-32 ----
        u32 bits = 0;
        #pragma unroll
        for (int s = 0; s < BEAM; ++s)
            if (ev[s] >= thr) bits |= (1u << s);
        if (lane < BEAM && st_tot >= thr) bits |= (1u << 16);
        int mycnt = __popc(bits);
        if (lane == 0) cntL = 0u;        // same-wave DS ordering precedes atomics
        u32 base = 0;
        if (mycnt) base = atomicAdd(&cntL, (u32)mycnt);
        #pragma unroll
        for (int s = 0; s < BEAM; ++s)
            if (bits & (1u << s)) {
                if (base < 64u) slotsL[base] = pack_key(ev[s], BEAM + s * NC + lane);
                ++base;
            }
        if (bits & (1u << 16)) {
            if (base < 64u) slotsL[base] = pack_key(st_tot, lane);
            ++base;
        }
        __syncthreads();
        u32 totc = cntL;                 // broadcast read, wave-uniform

        int flat; float val;
        if (totc <= 32u) {
            u64 kk = (lane < 32 && (u32)lane < totc) ? slotsL[lane] : 0ull;
            // bitonic sort-32 descending in lanes 0-31 (R4-proven CE pattern);
            // lanes 32-63 mirror harmlessly (xor masks < 32 keep halves apart).
            #pragma unroll
            for (int k = 2; k <= 32; k <<= 1) {
                #pragma unroll
                for (int j = k >> 1; j >= 1; j >>= 1) {
                    bool up = ((lane & k) == 0);
                    bool km = (((lane & j) == 0) == up);
                    u64 o = (u64)__shfl_xor((long long)kk, j, 64);
                    bool take = km ? (o > kk) : (o < kk);
                    kk = take ? o : kk;
                }
            }
            flat = key_flat(kk);         // lane r (0-15) holds rank r
            val  = key_val(kk);
        } else {
            // ---- exact u64 fallback (R3-proven), ~never ----
            u64 ku[BEAM];
            #pragma unroll
            for (int s = 0; s < BEAM; ++s)
                ku[s] = pack_key(ev[s], BEAM + s * NC + lane);
            sort16_desc_u64(ku);
            u64 sk = (lane < BEAM) ? pack_key(st_tot, lane) : 0ull;
            #pragma unroll
            for (int i = BEAM - 1; i >= 1; --i)
                ku[i] = max64(ku[i], min64(ku[i - 1], sk));
            ku[0] = max64(ku[0], sk);
            #pragma unroll 1
            for (int m = 1; m < 64; m <<= 1) {
                u64 c_[BEAM];
                #pragma unroll
                for (int i = 0; i < BEAM; ++i) {
                    u64 o = (u64)__shfl_xor((long long)ku[BEAM - 1 - i], m, 64);
                    c_[i] = max64(ku[i], o);
                }
                #pragma unroll
                for (int j = 8; j > 0; j >>= 1) {
                    #pragma unroll
                    for (int i = 0; i < BEAM; ++i)
                        if ((i & j) == 0) {
                            u64 xk = c_[i], yk = c_[i | j];
                            bool sw = xk < yk;
                            c_[i]     = sw ? yk : xk;
                            c_[i | j] = sw ? xk : yk;
                        }
                }
                #pragma unroll
                for (int i = 0; i < BEAM; ++i) ku[i] = c_[i];
            }
            u64 selkey = ku[0];
            #pragma unroll
            for (int i = 1; i < BEAM; ++i)
                if (lane == i) selkey = ku[i];
            flat = key_flat(selkey);
            val  = key_val(selkey);
        }

        // ---- predictor update from the EXACT selection (any path) ----
        {
            float v1n  = rdl_f(val, 0);
            float v16n = rdl_f(val, 15);
            spread = (v1n - v16n) * 1.25f + 1.0e-3f;
        }

        // ---- new state (lane k = rank-k winner) ----
        bool stay = flat < BEAM;
        int pidx = stay ? flat : ((flat - BEAM) >> 6);
        pidx &= 15;
        int cnew = stay ? 0 : ((flat - BEAM) & 63);

        // variable-index gathers (bpermute), all independent -> one wait
        float g_stpb  = __shfl(st_pb, pidx, 64);
        float g_stpnb = __shfl(st_pnb, pidx, 64);
        u32   g_h1    = (u32)__shfl((int)h1, pidx, 64);
        u32   g_h2    = (u32)__shfl((int)h2, pidx, 64);
        int   g_ll    = __shfl((lenb << 8) | (lastb & 255), pidx, 64);
        int   g_len   = g_ll >> 8;
        int   g_last  = (int)((signed char)(g_ll & 255));

        pb   = stay ? g_stpb : NEG;
        pnb  = stay ? g_stpnb : val;
        h1   = stay ? g_h1 : (g_h1 * 1000003u + (u32)(cnew + 1));
        h2   = stay ? g_h2 : (g_h2 * 69069u   + (u32)(cnew + 1));
        lenb = g_len + (stay ? 0 : 1);
        lastb = stay ? g_last : cnew;
        actb = (val > -5.0e8f) ? 1 : 0;              // vals > NEG/2
        if (lane < BEAM)
            hist[t * BEAM + lane] =
                (unsigned short)((pidx << 8) | (stay ? 0x80 : 0) | cnew);
    }
    __syncthreads();

    // ---- final stable top-4 over beam totals ----
    float ft = (lane < BEAM) ? log_add_exp(pb, pnb) : -FLTMAX;
    int fidx = (lane < BEAM) ? lane : 0x7FFFFFFF;
    for (int k = 0; k < TOPK; ++k) {
        float bv = ft; int bi = fidx;
        #pragma unroll
        for (int m = 1; m < 64; m <<= 1) {
            float ov = __shfl_xor(bv, m, 64);
            int   oi = __shfl_xor(bi, m, 64);
            if (ov > bv || (ov == bv && oi < bi)) { bv = ov; bi = oi; }
        }
        if (lane == 0) { ord4[k] = bi; val4[k] = bv; }
        if (lane == bi) ft = -FLTMAX;
    }
    __syncthreads();

    int bsel = ord4[lane & 3] & 15;
    int lensel = __shfl(lenb, bsel, 64);

    // ---- outputs: probs [B,4] | lens [B,4] | labels [B,4,256] ----
    for (int e2 = lane; e2 < TOPK * T_MAX; e2 += 64)
        out[BATCH * TOPK * 2 + b * (TOPK * T_MAX) + e2] = -1.0f;
    __syncthreads();
    if (lane < TOPK) {
        const int k = lane;
        out[b * TOPK + k] = -val4[k];
        out[BATCH * TOPK + b * TOPK + k] = (float)lensel;
        int pos = lensel - 1;
        int cur = ord4[k];
        float* lab = out + BATCH * TOPK * 2 + b * (TOPK * T_MAX) + k * T_MAX;
        for (int tt = len - 1; tt >= 0; --tt) {
            unsigned short h = hist[tt * BEAM + cur];
            if (!(h & 0x80)) { lab[pos] = (float)(h & 0x7F); --pos; }
            cur = h >> 8;
        }
    }
}

extern "C" void kernel_launch(void* const* d_in, const int* in_sizes, int n_in,
                              void* d_out, int out_size, void* d_ws, size_t ws_size,
                              hipStream_t stream) {
    const float* data = (const float*)d_in[0];
    const int* data_len = (const int*)d_in[1];
    float* out = (float*)d_out;
    const size_t lp_bytes = (size_t)T_MAX * BATCH * NC * sizeof(float);
    if (ws_size >= lp_bytes) {
        float* lp_ws = (float*)d_ws;
        softmax_kernel<<<dim3(T_MAX * BATCH), dim3(64), 0, stream>>>(data, lp_ws);
        ctc_beam_kernel<true><<<dim3(BATCH), dim3(64), 0, stream>>>(data, lp_ws, data_len, out);
    } else {
        ctc_beam_kernel<false><<<dim3(BATCH), dim3(64), 0, stream>>>(data, nullptr, data_len, out);
    }
}